// Round 5
// baseline (510.170 us; speedup 1.0000x reference)
//
#include <hip/hip_runtime.h>
#include <float.h>

#define BATCH 16
#define NPTS  65536
#define NP    64      // NUM_PATCHES
#define PS    32      // PATCH_SIZE
#define SLICES 8
#define SLICE_PTS (NPTS / SLICES)   // 8192
#define CAP   192                   // per (center,slice) candidate cap (exp ~40)

// Selection math (FPS argmax, KNN top-32) is float64 on f32 inputs (products
// of f32 exact in f64 -> bit-identical to numpy f64 regardless of FMA), with
// numpy expression order: ((a+b)+c), d2 = (c2+p2) - 2*dot, contract(off).
// Keys: trunc-48-bit f64 ordering bits | 16-bit index -> (dist, idx) lex order.

__device__ __forceinline__ unsigned long long enc64(double d) {
    unsigned long long u = (unsigned long long)__double_as_longlong(d);
    return u ^ ((u >> 63) ? 0xFFFFFFFFFFFFFFFFull : 0x8000000000000000ull);
}
__device__ __forceinline__ unsigned enc32(float f) {
    unsigned u = __float_as_uint(f);
    return u ^ ((u >> 31) ? 0xFFFFFFFFu : 0x80000000u);
}
__device__ __forceinline__ float dec32(unsigned e) {
    unsigned u = (e & 0x80000000u) ? (e ^ 0x80000000u) : ~e;
    return __uint_as_float(u);
}

#define SENT 0xFFFFFFFFFFFFFFFFull

// ---------------------------------------------------------------------------
// FPS v3 (pair speculation): 16 WGs per batch (blockIdx = wg*16+b), 256 thr,
// 16 pts/thread in VGPRs, v1's sync hierarchy (R2 lesson: mailbox wants few
// writers/pollers + s_sleep backoff). NEW: each round reduces the global
// TOP-2 (p = argmax key B1, q = runner-up key B2 with dist v_q). Gate: if
// d(q,p) > v_q then after selecting p every point's md only shrinks while
// md'_q = min(v_q, d(q,p)) = v_q stays the maximum, and any point tied at
// v_q already lost to q by the idx-in-key ordering -> q is provably the next
// argmax pick: take BOTH p,q in one sync round. v_q is only known truncated
// to 48 bits, so gate uses the conservative upper bound (trunc+2^16 in enc
// space) -> speculation never fires unless exact-f64 ordering guarantees it.
// Dual update min(min(md,d_p),d_q) == the two sequential rounds' fmin chain
// (exact f64, same order) -> selection stream bit-identical to v1.
// Slots: [16][63][16][2] (two keys per wg per round), zeroed. Keys have MSB
// set -> nonzero, so "both words nonzero" = posted.
// ---------------------------------------------------------------------------
__global__ __launch_bounds__(256, 2)
void fps_kernel(const float* __restrict__ pts,
                float* __restrict__ centers,               // [16][64][3]
                unsigned long long* __restrict__ slots)    // [16][63][16][2], zeroed
{
#pragma clang fp contract(off)
    const int b  = blockIdx.x & 15;
    const int wg = blockIdx.x >> 4;
    const int t  = threadIdx.x;
    const float* __restrict__ P = pts + (size_t)b * NPTS * 3;

    float x[16], y[16], z[16];
    double md[16];
    const int gi0 = wg * 4096 + t;
#pragma unroll
    for (int k = 0; k < 16; ++k) {
        int i = gi0 + (k << 8);
        x[k] = P[3*i+0]; y[k] = P[3*i+1]; z[k] = P[3*i+2];
        md[k] = DBL_MAX;
    }

    double cx = (double)P[0], cy = (double)P[1], cz = (double)P[2]; // start idx 0
    double qx = 0.0, qy = 0.0, qz = 0.0;
    bool dual = false;
    if (wg == 0 && t == 0) {
        float* c0 = centers + b * (NP*3);
        c0[0] = P[0]; c0[1] = P[1]; c0[2] = P[2];
    }

    __shared__ unsigned long long wk1[4], wk2[4];
    __shared__ unsigned long long sk1[16], sk2[16];

    unsigned long long* slot_it = slots + (size_t)b * 63 * 32;

    int nsel = 1;
    while (nsel < NP) {
        // ---- update md (1 or 2 new picks) + per-thread top-2 ----
        double bd1 = -1.0, bd2 = -1.0; int bi1 = 0, bi2 = 0;
#pragma unroll
        for (int k = 0; k < 16; ++k) {
            double dx = (double)x[k] - cx;
            double dy = (double)y[k] - cy;
            double dz = (double)z[k] - cz;
            double d  = (dx*dx + dy*dy) + dz*dz;   // numpy add order
            double m  = fmin(md[k], d);
            if (dual) {
                double ex = (double)x[k] - qx;
                double ey = (double)y[k] - qy;
                double ez = (double)z[k] - qz;
                double e  = (ex*ex + ey*ey) + ez*ez;
                m = fmin(m, e);                     // == next round's fmin
            }
            md[k] = m;
            int i = gi0 + (k << 8);
            if (m > bd1)      { bd2 = bd1; bi2 = bi1; bd1 = m; bi1 = i; } // strict >: first idx wins
            else if (m > bd2) { bd2 = m;  bi2 = i; }
        }
        unsigned long long k1 = 0x8000000000000000ull
            | ((unsigned long long)__double_as_longlong(bd1) & 0xFFFFFFFFFFFF0000ull)
            | (unsigned long long)((~bi1) & 0xFFFF);
        unsigned long long k2 = 0x8000000000000000ull
            | ((unsigned long long)__double_as_longlong(bd2) & 0xFFFFFFFFFFFF0000ull)
            | (unsigned long long)((~bi2) & 0xFFFF);

        // ---- wave top-2 (two xor-max reductions; keys unique by idx) ----
        unsigned long long K1 = k1;
#pragma unroll
        for (int off = 32; off > 0; off >>= 1) {
            unsigned long long o = __shfl_xor(K1, off, 64);
            if (o > K1) K1 = o;
        }
        unsigned long long K2 = (k1 == K1) ? k2 : k1;  // owner contributes its 2nd
#pragma unroll
        for (int off = 32; off > 0; off >>= 1) {
            unsigned long long o = __shfl_xor(K2, off, 64);
            if (o > K2) K2 = o;
        }
        if ((t & 63) == 0) { wk1[t >> 6] = K1; wk2[t >> 6] = K2; }
        __syncthreads();                                   // bar1
        if (t == 0) {
            unsigned long long B1 = 0, B2 = 0;
#pragma unroll
            for (int j = 0; j < 4; ++j) {
                unsigned long long a = wk1[j];
                if (a > B1) { B2 = B1; B1 = a; } else if (a > B2) B2 = a;
                unsigned long long c = wk2[j];
                if (c > B1) { B2 = B1; B1 = c; } else if (c > B2) B2 = c;
            }
            __hip_atomic_store(slot_it + wg*2 + 0, B1, __ATOMIC_RELAXED, __HIP_MEMORY_SCOPE_AGENT);
            __hip_atomic_store(slot_it + wg*2 + 1, B2, __ATOMIC_RELAXED, __HIP_MEMORY_SCOPE_AGENT);
        }
        if (t < 16) {
            unsigned long long v1, v2;
            v1 = __hip_atomic_load(slot_it + t*2 + 0, __ATOMIC_RELAXED, __HIP_MEMORY_SCOPE_AGENT);
            while (v1 == 0) {
                __builtin_amdgcn_s_sleep(1);
                v1 = __hip_atomic_load(slot_it + t*2 + 0, __ATOMIC_RELAXED, __HIP_MEMORY_SCOPE_AGENT);
            }
            v2 = __hip_atomic_load(slot_it + t*2 + 1, __ATOMIC_RELAXED, __HIP_MEMORY_SCOPE_AGENT);
            while (v2 == 0) {
                __builtin_amdgcn_s_sleep(1);
                v2 = __hip_atomic_load(slot_it + t*2 + 1, __ATOMIC_RELAXED, __HIP_MEMORY_SCOPE_AGENT);
            }
            sk1[t] = v1; sk2[t] = v2;
        }
        __syncthreads();                                   // bar2
        // ---- global top-2 over 32 posted keys (uniform, redundant/thread) ----
        unsigned long long B1 = 0, B2 = 0;
#pragma unroll
        for (int j = 0; j < 16; ++j) {
            unsigned long long a = sk1[j];
            if (a > B1) { B2 = B1; B1 = a; } else if (a > B2) B2 = a;
            unsigned long long c = sk2[j];
            if (c > B1) { B2 = B1; B1 = c; } else if (c > B2) B2 = c;
        }
        int sel1 = (int)((~B1) & 0xFFFFull);
        cx = (double)P[3*sel1+0]; cy = (double)P[3*sel1+1]; cz = (double)P[3*sel1+2];
        if (wg == 0 && t == 0) {
            float* c = centers + b*(NP*3) + nsel*3;
            c[0] = P[3*sel1+0]; c[1] = P[3*sel1+1]; c[2] = P[3*sel1+2];
        }
        // ---- speculation gate (uniform across all WGs/threads) ----
        dual = false;
        if (nsel + 2 <= NP) {
            int sel2 = (int)((~B2) & 0xFFFFull);
            qx = (double)P[3*sel2+0]; qy = (double)P[3*sel2+1]; qz = (double)P[3*sel2+2];
            double gx = qx - cx, gy = qy - cy, gz = qz - cz;
            double d21 = (gx*gx + gy*gy) + gz*gz;          // exact f64, same expr
            unsigned long long encd = (unsigned long long)__double_as_longlong(d21)
                                    | 0x8000000000000000ull;    // enc64, d21>=0
            unsigned long long ub = (B2 & 0xFFFFFFFFFFFF0000ull) + 0x10000ull; // > enc(v_q)
            if (encd >= ub) {
                dual = true;
                if (wg == 0 && t == 0) {
                    float* c = centers + b*(NP*3) + (nsel+1)*3;
                    c[0] = P[3*sel2+0]; c[1] = P[3*sel2+1]; c[2] = P[3*sel2+2];
                }
            }
        }
        nsel += dual ? 2 : 1;
        slot_it += 32;
        // no trailing barrier: next round's bar1 orders sk/wk reuse
    }
}

// ---------------------------------------------------------------------------
// KNN pass (R3 known-good; R4's CG=16 restructure regressed — 2 waves/SIMD
// could not hide latency of long dependency blocks, occupancy slack beats
// fewer-WG re-streaming savings). 2048 WGs x 256 thr. blockIdx: b=&15
// (XCD-local batch), w=(>>4)&15 (center group of 4), s=>>8 (slice of 8192).
// Hot loops: register double-buffer prefetch of k+1's three float4 loads.
// Pass 1: f32 per-thread top-2 -> WG pool (512/center) -> theta = pool 32nd
// + 4e-3. Pass 2: f32 rescan, per-lane atomicAdd compaction (order-free:
// phase 3 sorts by full (dist|idx) key). Phase 3: wave g exact f64 keys for
// <=CAP candidates (3/lane), top-32 sorted -> gkeys[c][s][32].
// ---------------------------------------------------------------------------
__global__ __launch_bounds__(256, 4)
void knn_pass(const float* __restrict__ pts,
              const float* __restrict__ centers,
              unsigned long long* __restrict__ gkeys)   // [1024][8][32]
{
    const int t    = threadIdx.x;
    const int lane = t & 63;
    const int wid  = t >> 6;             // 0..3
    const int b    = blockIdx.x & 15;
    const int w    = (blockIdx.x >> 4) & 15;
    const int s    = blockIdx.x >> 8;    // 0..7
    const float* __restrict__ P = pts + (size_t)b * NPTS * 3;
    const int sbase = s * SLICE_PTS;
    const float4* __restrict__ P4 = (const float4*)(P + 3 * sbase);

    float cxf[4], cyf[4], czf[4], c2f[4];
#pragma unroll
    for (int g = 0; g < 4; ++g) {
        int c = b * NP + w * 4 + g;
        cxf[g] = centers[3*c+0]; cyf[g] = centers[3*c+1]; czf[g] = centers[3*c+2];
        c2f[g] = cxf[g]*cxf[g] + cyf[g]*cyf[g] + czf[g]*czf[g];
    }

    __shared__ unsigned pool[4][512];
    __shared__ float    theta4[4];
    __shared__ int      cnt4[4];
    __shared__ unsigned idxbuf[4][CAP];

    // ---- pass 1: per-thread top-2 (f32), 4 pts/iter, prefetch k+1 ----
    float s0[4], s1[4];
#pragma unroll
    for (int g = 0; g < 4; ++g) { s0[g] = FLT_MAX; s1[g] = FLT_MAX; }
    {
        float4 A = P4[3*t], B = P4[3*t+1], C = P4[3*t+2];
        for (int k = 0; k < SLICE_PTS/1024; ++k) {       // 8 iterations
            int vb = ((k+1) & 7)*768 + 3*t;              // wrap: last prefetch discarded
            float4 An = P4[vb], Bn = P4[vb+1], Cn = P4[vb+2];
            float qx[4] = {A.x, A.w, B.z, C.y};
            float qy[4] = {A.y, B.x, B.w, C.z};
            float qz[4] = {A.z, B.y, C.x, C.w};
#pragma unroll
            for (int j = 0; j < 4; ++j) {
                float px = qx[j], py = qy[j], pz = qz[j];
                float p2 = px*px + py*py + pz*pz;
#pragma unroll
                for (int g = 0; g < 4; ++g) {
                    float dt = cxf[g]*px + cyf[g]*py + czf[g]*pz;
                    float d2 = (c2f[g] + p2) - 2.0f*dt;
                    float mx = fmaxf(d2, s0[g]);
                    s0[g] = fminf(s0[g], d2);
                    s1[g] = fminf(s1[g], mx);
                }
            }
            A = An; B = Bn; C = Cn;
        }
    }
#pragma unroll
    for (int g = 0; g < 4; ++g) {
        pool[g][t]       = enc32(s0[g]);
        pool[g][256 + t] = enc32(s1[g]);
    }
    if (t < 4) cnt4[t] = 0;
    __syncthreads();

    // ---- theta: wave wid finds 32nd smallest of pool[wid][0..511] ----
    {
        const int g = wid;
        unsigned e[8];
#pragma unroll
        for (int j = 0; j < 8; ++j) e[j] = pool[g][lane * 8 + j];
        unsigned ans = 0;
        for (int bit = 31; bit >= 0; --bit) {
            unsigned test = ans | ((1u << bit) - 1u);
            int cnt = 0;
#pragma unroll
            for (int j = 0; j < 8; ++j)
                cnt += (int)__popcll(__ballot(e[j] <= test));
            if (cnt < 32) ans |= (1u << bit);
        }
        if (lane == 0) theta4[g] = dec32(ans) + 4.0e-3f;
    }
    __syncthreads();
    float th[4];
#pragma unroll
    for (int g = 0; g < 4; ++g) th[g] = theta4[g];

    // ---- pass 2: f32 rescan with prefetch, atomicAdd compaction ----
    {
        float4 A = P4[3*t], B = P4[3*t+1], C = P4[3*t+2];
        for (int k = 0; k < SLICE_PTS/1024; ++k) {
            int vb = ((k+1) & 7)*768 + 3*t;
            float4 An = P4[vb], Bn = P4[vb+1], Cn = P4[vb+2];
            float qx[4] = {A.x, A.w, B.z, C.y};
            float qy[4] = {A.y, B.x, B.w, C.z};
            float qz[4] = {A.z, B.y, C.x, C.w};
            int ib = sbase + (k << 10) + (t << 2);
#pragma unroll
            for (int j = 0; j < 4; ++j) {
                float px = qx[j], py = qy[j], pz = qz[j];
                float p2 = px*px + py*py + pz*pz;
#pragma unroll
                for (int g = 0; g < 4; ++g) {
                    float dt = cxf[g]*px + cyf[g]*py + czf[g]*pz;
                    float d2 = (c2f[g] + p2) - 2.0f*dt;
                    if (d2 <= th[g]) {
                        int pos = atomicAdd(&cnt4[g], 1);
                        if (pos < CAP) idxbuf[g][pos] = (unsigned)(ib + j);
                    }
                }
            }
            A = An; B = Bn; C = Cn;
        }
    }
    __syncthreads();

    // ---- phase 3: wave wid -> center wid: exact f64 keys, top-32 sorted ----
    {
        const int g = wid;
        int n = cnt4[g]; if (n > CAP) n = CAP;
        double cxd, cyd, czd, c2d;
        {
#pragma clang fp contract(off)
            cxd = (double)cxf[g]; cyd = (double)cyf[g]; czd = (double)czf[g];
            c2d = (cxd*cxd + cyd*cyd) + czd*czd;
        }
        unsigned long long rg[3];
#pragma unroll
        for (int j = 0; j < 3; ++j) {
            int p_ = lane + 64*j;
            if (p_ < n) {
                unsigned i = idxbuf[g][p_];
                double d2x;
                {
#pragma clang fp contract(off)
                    double px_ = (double)P[3*i+0];
                    double py_ = (double)P[3*i+1];
                    double pz_ = (double)P[3*i+2];
                    double p2_ = (px_*px_ + py_*py_) + pz_*pz_;
                    double dt_ = (cxd*px_ + cyd*py_) + czd*pz_;
                    d2x = (c2d + p2_) - 2.0*dt_;
                }
                rg[j] = (enc64(d2x) & 0xFFFFFFFFFFFF0000ull)
                      | (unsigned long long)(i & 0xFFFF);
            } else rg[j] = SENT;
        }
        const int c = b * NP + w * 4 + g;
        unsigned long long okey = SENT;
        for (int r = 0; r < PS; ++r) {
            unsigned long long mn = rg[0]; int mp = 0;
            if (rg[1] < mn) { mn = rg[1]; mp = 1; }
            if (rg[2] < mn) { mn = rg[2]; mp = 2; }
            unsigned long long wm = mn;
#pragma unroll
            for (int off = 32; off > 0; off >>= 1) {
                unsigned long long o = __shfl_xor(wm, off, 64);
                if (o < wm) wm = o;
            }
            if (wm == mn) {               // unique owner (idx in key)
                if (mp == 0) rg[0] = SENT;
                else if (mp == 1) rg[1] = SENT;
                else rg[2] = SENT;
            }
            if (lane == r) okey = wm;
        }
        if (lane < PS)
            gkeys[((size_t)c * SLICES + s) * PS + lane] = okey;
    }
}

// ---------------------------------------------------------------------------
// Merge: 256 WGs x 256 thr; wave wid handles center b*64+grp*4+wid. Reads 8
// sorted 32-key lists (256 keys, 4/lane), 32 extraction rounds -> global
// top-32 in lax.top_k order; lanes 0..31 gather P and write patch rows.
// ---------------------------------------------------------------------------
__global__ __launch_bounds__(256, 4)
void knn_merge(const float* __restrict__ pts,
               const float* __restrict__ centers,
               const unsigned long long* __restrict__ gkeys,
               float* __restrict__ patches)
{
    const int lane = threadIdx.x & 63;
    const int wid  = threadIdx.x >> 6;
    const int b    = blockIdx.x & 15;
    const int grp  = blockIdx.x >> 4;
    const int c    = b * NP + grp * 4 + wid;
    const float* __restrict__ P = pts + (size_t)b * NPTS * 3;

    unsigned long long rg[4];
#pragma unroll
    for (int j = 0; j < 4; ++j)
        rg[j] = gkeys[(size_t)c * (SLICES*PS) + j*64 + lane];

    unsigned long long okey = SENT;
    for (int r = 0; r < PS; ++r) {
        unsigned long long mn = rg[0]; int mp = 0;
        if (rg[1] < mn) { mn = rg[1]; mp = 1; }
        if (rg[2] < mn) { mn = rg[2]; mp = 2; }
        if (rg[3] < mn) { mn = rg[3]; mp = 3; }
        unsigned long long wm = mn;
#pragma unroll
        for (int off = 32; off > 0; off >>= 1) {
            unsigned long long o = __shfl_xor(wm, off, 64);
            if (o < wm) wm = o;
        }
        if (wm == mn) {
            if (mp == 0) rg[0] = SENT;
            else if (mp == 1) rg[1] = SENT;
            else if (mp == 2) rg[2] = SENT;
            else rg[3] = SENT;
        }
        if (lane == r) okey = wm;
    }

    const float cx = centers[3*c+0], cy = centers[3*c+1], cz = centers[3*c+2];
    if (lane < PS) {
        int i = (int)(okey & 0xFFFFull);
        float* o = patches + (((size_t)c * PS) + lane) * 3;
        o[0] = P[3*i+0] - cx;
        o[1] = P[3*i+1] - cy;
        o[2] = P[3*i+2] - cz;
    }
}

extern "C" void kernel_launch(void* const* d_in, const int* in_sizes, int n_in,
                              void* d_out, int out_size, void* d_ws, size_t ws_size,
                              hipStream_t stream)
{
    const float* pts = (const float*)d_in[0];
    float* out      = (float*)d_out;
    float* patches  = out;                          // [16][64][32][3] = 98304
    float* centers  = out + (size_t)BATCH*NP*PS*3;  // [16][64][3]     = 3072

    unsigned long long* slots = (unsigned long long*)d_ws;                   // 258 KB
    unsigned long long* gkeys = (unsigned long long*)((char*)d_ws + 262144); // 2 MB

    (void)hipMemsetAsync(d_ws, 0, (size_t)BATCH * 63 * 16 * 2 * sizeof(unsigned long long), stream);
    fps_kernel<<<dim3(256), dim3(256), 0, stream>>>(pts, centers, slots);
    knn_pass<<<dim3(2048), dim3(256), 0, stream>>>(pts, centers, gkeys);
    knn_merge<<<dim3(256), dim3(256), 0, stream>>>(pts, centers, gkeys, patches);
}

// Round 6
// 293.465 us; speedup vs baseline: 1.7384x; 1.7384x over previous
//
#include <hip/hip_runtime.h>
#include <float.h>

#define BATCH 16
#define NPTS  65536
#define NP    64      // NUM_PATCHES
#define PS    32      // PATCH_SIZE
#define SLICES 8
#define SLICE_PTS (NPTS / SLICES)   // 8192
#define CAP   192                   // per (center,slice) candidate cap (exp ~40)

// DIAGNOSTIC ROUND (R6): knn_pass streaming passes run 2x (reps) so knn_pass
// exceeds fps (117us) and surfaces in the duration-sorted top-5 with real
// counters. Output is provably identical (rep re-inits state; keep-alive asm
// prevents rep-0 DCE). Remove REPS in R7 once counters are read.
#define REPS 2

// Selection math (FPS argmax, KNN top-32) is float64 on f32 inputs (products
// of f32 exact in f64 -> bit-identical to numpy f64 regardless of FMA), with
// numpy expression order: ((a+b)+c), d2 = (c2+p2) - 2*dot, contract(off).
// Keys: trunc-48-bit f64 ordering bits | 16-bit index -> (dist, idx) lex order.

__device__ __forceinline__ unsigned long long enc64(double d) {
    unsigned long long u = (unsigned long long)__double_as_longlong(d);
    return u ^ ((u >> 63) ? 0xFFFFFFFFFFFFFFFFull : 0x8000000000000000ull);
}
__device__ __forceinline__ unsigned enc32(float f) {
    unsigned u = __float_as_uint(f);
    return u ^ ((u >> 31) ? 0xFFFFFFFFu : 0x80000000u);
}
__device__ __forceinline__ float dec32(unsigned e) {
    unsigned u = (e & 0x80000000u) ? (e ^ 0x80000000u) : ~e;
    return __uint_as_float(u);
}

#define SENT 0xFFFFFFFFFFFFFFFFull

// ---------------------------------------------------------------------------
// FPS (v1, known-good 117us — PERMANENT: sync-restructure 0-for-3, R2/R5
// post-mortems; 117us ~ 1.25x the 63-round cross-CU sync floor). 16 WGs per
// batch (blockIdx = wg*16+b -> all WGs of batch b on XCD b%8), 256 threads,
// 16 pts/thread in VGPRs. Relaxed agent atomics only. 2 barriers per round.
// ---------------------------------------------------------------------------
__global__ __launch_bounds__(256, 2)
void fps_kernel(const float* __restrict__ pts,
                float* __restrict__ centers,               // [16][64][3]
                unsigned long long* __restrict__ slots)    // [16][63][16], zeroed
{
#pragma clang fp contract(off)
    const int b  = blockIdx.x & 15;
    const int wg = blockIdx.x >> 4;
    const int t  = threadIdx.x;
    const float* __restrict__ P = pts + (size_t)b * NPTS * 3;

    float x[16], y[16], z[16];
    double md[16];
    const int gi0 = wg * 4096 + t;
#pragma unroll
    for (int k = 0; k < 16; ++k) {
        int i = gi0 + (k << 8);
        x[k] = P[3*i+0]; y[k] = P[3*i+1]; z[k] = P[3*i+2];
        md[k] = DBL_MAX;
    }

    double cx = (double)P[0], cy = (double)P[1], cz = (double)P[2]; // start idx 0
    if (wg == 0 && t == 0) {
        float* c0 = centers + b * (NP*3);
        c0[0] = P[0]; c0[1] = P[1]; c0[2] = P[2];
    }

    __shared__ unsigned long long wbest[4];
    __shared__ unsigned long long skey[16];

    unsigned long long* slot_it = slots + (size_t)b * 63 * 16;

    for (int it = 0; it < NP - 1; ++it) {
        double bd = -1.0; int bi = 0;
#pragma unroll
        for (int k = 0; k < 16; ++k) {
            double dx = (double)x[k] - cx;
            double dy = (double)y[k] - cy;
            double dz = (double)z[k] - cz;
            double d  = (dx*dx + dy*dy) + dz*dz;   // numpy add order (products exact)
            double m  = fmin(md[k], d);
            md[k] = m;
            if (m > bd) { bd = m; bi = gi0 + (k << 8); }  // strict >: first index wins
        }
        unsigned long long db  = (unsigned long long)__double_as_longlong(bd); // bd>=0
        unsigned long long key = 0x8000000000000000ull
                               | (db & 0xFFFFFFFFFFFF0000ull)
                               | (unsigned long long)((~bi) & 0xFFFF);
#pragma unroll
        for (int off = 32; off > 0; off >>= 1) {
            unsigned long long o = __shfl_xor(key, off, 64);
            if (o > key) key = o;
        }
        if ((t & 63) == 0) wbest[t >> 6] = key;
        __syncthreads();                                   // bar1
        if (t == 0) {
            unsigned long long k0 = wbest[0];
            if (wbest[1] > k0) k0 = wbest[1];
            if (wbest[2] > k0) k0 = wbest[2];
            if (wbest[3] > k0) k0 = wbest[3];
            __hip_atomic_store(slot_it + wg, k0, __ATOMIC_RELAXED, __HIP_MEMORY_SCOPE_AGENT);
        }
        if (t < 16) {
            unsigned long long v;
            v = __hip_atomic_load(slot_it + t, __ATOMIC_RELAXED, __HIP_MEMORY_SCOPE_AGENT);
            while (v == 0) {
                __builtin_amdgcn_s_sleep(1);
                v = __hip_atomic_load(slot_it + t, __ATOMIC_RELAXED, __HIP_MEMORY_SCOPE_AGENT);
            }
            skey[t] = v;
        }
        __syncthreads();                                   // bar2
        unsigned long long bk = skey[0];
#pragma unroll
        for (int j = 1; j < 16; ++j) if (skey[j] > bk) bk = skey[j];
        int sel = (int)((~bk) & 0xFFFFull);
        cx = (double)P[3*sel+0]; cy = (double)P[3*sel+1]; cz = (double)P[3*sel+2];
        if (wg == 0 && t == 0) {
            float* c = centers + b*(NP*3) + (it+1)*3;
            c[0] = P[3*sel+0]; c[1] = P[3*sel+1]; c[2] = P[3*sel+2];
        }
        slot_it += 16;
        // no trailing barrier: next round's bar1 orders skey/wbest reuse
    }
}

// ---------------------------------------------------------------------------
// KNN pass (R3 structure, CG=4, 2048 WGs x 256 thr) + R6 DIAGNOSTIC REPS.
// blockIdx: b=&15 (XCD-local batch), w=(>>4)&15, s=>>8.
// Pass 1: f32 per-thread top-2 -> WG pool (512/center) -> theta = pool 32nd
// + 4e-3. NEW (exact-identical): s1 update via med3 — for s0<=s1:
//   d2<=s0: old s1'=min(s1,max(d2,s0))=min(s1,s0)=s0 ; med3(s0,s1,d2)=s0 ok
//   s0<d2<=s1: old s1'=min(s1,d2)=d2 ; med3=d2 ok
//   d2>s1: old s1'=min(s1,d2)=s1 ; med3=s1 ok      (2 ops vs 3)
// Pass 2: f32 rescan, per-lane atomicAdd compaction (order-free: phase 3
// sorts by full (dist|idx) key). Phase 3: wave g exact f64 keys for <=CAP
// candidates (3/lane), top-32 sorted -> gkeys[c][s][32].
// REPS: each streaming pass runs twice with re-initialized state; rep-0 kept
// observable via asm passthrough (DCE guard, rule 17); pass-2 reps separated
// by barriers around the cnt4 reset. Downstream state identical.
// ---------------------------------------------------------------------------
__global__ __launch_bounds__(256, 4)
void knn_pass(const float* __restrict__ pts,
              const float* __restrict__ centers,
              unsigned long long* __restrict__ gkeys)   // [1024][8][32]
{
    const int t    = threadIdx.x;
    const int lane = t & 63;
    const int wid  = t >> 6;             // 0..3
    const int b    = blockIdx.x & 15;
    const int w    = (blockIdx.x >> 4) & 15;
    const int s    = blockIdx.x >> 8;    // 0..7
    const float* __restrict__ P = pts + (size_t)b * NPTS * 3;
    const int sbase = s * SLICE_PTS;
    const float4* __restrict__ P4 = (const float4*)(P + 3 * sbase);

    float cxf[4], cyf[4], czf[4], c2f[4];
#pragma unroll
    for (int g = 0; g < 4; ++g) {
        int c = b * NP + w * 4 + g;
        cxf[g] = centers[3*c+0]; cyf[g] = centers[3*c+1]; czf[g] = centers[3*c+2];
        c2f[g] = cxf[g]*cxf[g] + cyf[g]*cyf[g] + czf[g]*czf[g];
    }

    __shared__ unsigned pool[4][512];
    __shared__ float    theta4[4];
    __shared__ int      cnt4[4];
    __shared__ unsigned idxbuf[4][CAP];

    // ---- pass 1 (xREPS): per-thread top-2 (f32), 4 pts/iter, prefetch ----
    float s0[4], s1[4];
    for (int rep = 0; rep < REPS; ++rep) {
#pragma unroll
        for (int g = 0; g < 4; ++g) { s0[g] = FLT_MAX; s1[g] = FLT_MAX; }
        float4 A = P4[3*t], B = P4[3*t+1], C = P4[3*t+2];
        for (int k = 0; k < SLICE_PTS/1024; ++k) {       // 8 iterations
            int vb = ((k+1) & 7)*768 + 3*t;              // wrap: last prefetch discarded
            float4 An = P4[vb], Bn = P4[vb+1], Cn = P4[vb+2];
            float qx[4] = {A.x, A.w, B.z, C.y};
            float qy[4] = {A.y, B.x, B.w, C.z};
            float qz[4] = {A.z, B.y, C.x, C.w};
#pragma unroll
            for (int j = 0; j < 4; ++j) {
                float px = qx[j], py = qy[j], pz = qz[j];
                float p2 = px*px + py*py + pz*pz;
#pragma unroll
                for (int g = 0; g < 4; ++g) {
                    float dt = cxf[g]*px + cyf[g]*py + czf[g]*pz;
                    float d2 = (c2f[g] + p2) - 2.0f*dt;
                    s1[g] = __builtin_amdgcn_fmed3f(s0[g], s1[g], d2);
                    s0[g] = fminf(s0[g], d2);
                }
            }
            A = An; B = Bn; C = Cn;
        }
        // keep rep-0's results observable so the compiler can't delete rep 0
#pragma unroll
        for (int g = 0; g < 4; ++g) {
            asm volatile("" : "+v"(s0[g]));
            asm volatile("" : "+v"(s1[g]));
        }
    }
#pragma unroll
    for (int g = 0; g < 4; ++g) {
        pool[g][t]       = enc32(s0[g]);
        pool[g][256 + t] = enc32(s1[g]);
    }
    __syncthreads();

    // ---- theta: wave wid finds 32nd smallest of pool[wid][0..511] ----
    {
        const int g = wid;
        unsigned e[8];
#pragma unroll
        for (int j = 0; j < 8; ++j) e[j] = pool[g][lane * 8 + j];
        unsigned ans = 0;
        for (int bit = 31; bit >= 0; --bit) {
            unsigned test = ans | ((1u << bit) - 1u);
            int cnt = 0;
#pragma unroll
            for (int j = 0; j < 8; ++j)
                cnt += (int)__popcll(__ballot(e[j] <= test));
            if (cnt < 32) ans |= (1u << bit);
        }
        if (lane == 0) theta4[g] = dec32(ans) + 4.0e-3f;
    }
    __syncthreads();
    float th[4];
#pragma unroll
    for (int g = 0; g < 4; ++g) th[g] = theta4[g];

    // ---- pass 2 (xREPS): f32 rescan, atomicAdd compaction ----
    for (int rep = 0; rep < REPS; ++rep) {
        __syncthreads();                     // rep>0: wait out prior rep's atomics
        if (t < 4) cnt4[t] = 0;
        __syncthreads();
        float4 A = P4[3*t], B = P4[3*t+1], C = P4[3*t+2];
        for (int k = 0; k < SLICE_PTS/1024; ++k) {
            int vb = ((k+1) & 7)*768 + 3*t;
            float4 An = P4[vb], Bn = P4[vb+1], Cn = P4[vb+2];
            float qx[4] = {A.x, A.w, B.z, C.y};
            float qy[4] = {A.y, B.x, B.w, C.z};
            float qz[4] = {A.z, B.y, C.x, C.w};
            int ib = sbase + (k << 10) + (t << 2);
#pragma unroll
            for (int j = 0; j < 4; ++j) {
                float px = qx[j], py = qy[j], pz = qz[j];
                float p2 = px*px + py*py + pz*pz;
#pragma unroll
                for (int g = 0; g < 4; ++g) {
                    float dt = cxf[g]*px + cyf[g]*py + czf[g]*pz;
                    float d2 = (c2f[g] + p2) - 2.0f*dt;
                    if (d2 <= th[g]) {
                        int pos = atomicAdd(&cnt4[g], 1);
                        if (pos < CAP) idxbuf[g][pos] = (unsigned)(ib + j);
                    }
                }
            }
            A = An; B = Bn; C = Cn;
        }
    }
    __syncthreads();

    // ---- phase 3: wave wid -> center wid: exact f64 keys, top-32 sorted ----
    {
        const int g = wid;
        int n = cnt4[g]; if (n > CAP) n = CAP;
        double cxd, cyd, czd, c2d;
        {
#pragma clang fp contract(off)
            cxd = (double)cxf[g]; cyd = (double)cyf[g]; czd = (double)czf[g];
            c2d = (cxd*cxd + cyd*cyd) + czd*czd;
        }
        unsigned long long rg[3];
#pragma unroll
        for (int j = 0; j < 3; ++j) {
            int p_ = lane + 64*j;
            if (p_ < n) {
                unsigned i = idxbuf[g][p_];
                double d2x;
                {
#pragma clang fp contract(off)
                    double px_ = (double)P[3*i+0];
                    double py_ = (double)P[3*i+1];
                    double pz_ = (double)P[3*i+2];
                    double p2_ = (px_*px_ + py_*py_) + pz_*pz_;
                    double dt_ = (cxd*px_ + cyd*py_) + czd*pz_;
                    d2x = (c2d + p2_) - 2.0*dt_;
                }
                rg[j] = (enc64(d2x) & 0xFFFFFFFFFFFF0000ull)
                      | (unsigned long long)(i & 0xFFFF);
            } else rg[j] = SENT;
        }
        const int c = b * NP + w * 4 + g;
        unsigned long long okey = SENT;
        for (int r = 0; r < PS; ++r) {
            unsigned long long mn = rg[0]; int mp = 0;
            if (rg[1] < mn) { mn = rg[1]; mp = 1; }
            if (rg[2] < mn) { mn = rg[2]; mp = 2; }
            unsigned long long wm = mn;
#pragma unroll
            for (int off = 32; off > 0; off >>= 1) {
                unsigned long long o = __shfl_xor(wm, off, 64);
                if (o < wm) wm = o;
            }
            if (wm == mn) {               // unique owner (idx in key)
                if (mp == 0) rg[0] = SENT;
                else if (mp == 1) rg[1] = SENT;
                else rg[2] = SENT;
            }
            if (lane == r) okey = wm;
        }
        if (lane < PS)
            gkeys[((size_t)c * SLICES + s) * PS + lane] = okey;
    }
}

// ---------------------------------------------------------------------------
// Merge: 256 WGs x 256 thr; wave wid handles center b*64+grp*4+wid. Reads 8
// sorted 32-key lists (256 keys, 4/lane), 32 extraction rounds -> global
// top-32 in lax.top_k order; lanes 0..31 gather P and write patch rows.
// ---------------------------------------------------------------------------
__global__ __launch_bounds__(256, 4)
void knn_merge(const float* __restrict__ pts,
               const float* __restrict__ centers,
               const unsigned long long* __restrict__ gkeys,
               float* __restrict__ patches)
{
    const int lane = threadIdx.x & 63;
    const int wid  = threadIdx.x >> 6;
    const int b    = blockIdx.x & 15;
    const int grp  = blockIdx.x >> 4;
    const int c    = b * NP + grp * 4 + wid;
    const float* __restrict__ P = pts + (size_t)b * NPTS * 3;

    unsigned long long rg[4];
#pragma unroll
    for (int j = 0; j < 4; ++j)
        rg[j] = gkeys[(size_t)c * (SLICES*PS) + j*64 + lane];

    unsigned long long okey = SENT;
    for (int r = 0; r < PS; ++r) {
        unsigned long long mn = rg[0]; int mp = 0;
        if (rg[1] < mn) { mn = rg[1]; mp = 1; }
        if (rg[2] < mn) { mn = rg[2]; mp = 2; }
        if (rg[3] < mn) { mn = rg[3]; mp = 3; }
        unsigned long long wm = mn;
#pragma unroll
        for (int off = 32; off > 0; off >>= 1) {
            unsigned long long o = __shfl_xor(wm, off, 64);
            if (o < wm) wm = o;
        }
        if (wm == mn) {
            if (mp == 0) rg[0] = SENT;
            else if (mp == 1) rg[1] = SENT;
            else if (mp == 2) rg[2] = SENT;
            else rg[3] = SENT;
        }
        if (lane == r) okey = wm;
    }

    const float cx = centers[3*c+0], cy = centers[3*c+1], cz = centers[3*c+2];
    if (lane < PS) {
        int i = (int)(okey & 0xFFFFull);
        float* o = patches + (((size_t)c * PS) + lane) * 3;
        o[0] = P[3*i+0] - cx;
        o[1] = P[3*i+1] - cy;
        o[2] = P[3*i+2] - cz;
    }
}

extern "C" void kernel_launch(void* const* d_in, const int* in_sizes, int n_in,
                              void* d_out, int out_size, void* d_ws, size_t ws_size,
                              hipStream_t stream)
{
    const float* pts = (const float*)d_in[0];
    float* out      = (float*)d_out;
    float* patches  = out;                          // [16][64][32][3] = 98304
    float* centers  = out + (size_t)BATCH*NP*PS*3;  // [16][64][3]     = 3072

    unsigned long long* slots = (unsigned long long*)d_ws;                   // 129 KB
    unsigned long long* gkeys = (unsigned long long*)((char*)d_ws + 131072); // 2 MB

    (void)hipMemsetAsync(d_ws, 0, (size_t)BATCH * 63 * 16 * sizeof(unsigned long long), stream);
    fps_kernel<<<dim3(256), dim3(256), 0, stream>>>(pts, centers, slots);
    knn_pass<<<dim3(2048), dim3(256), 0, stream>>>(pts, centers, gkeys);
    knn_merge<<<dim3(256), dim3(256), 0, stream>>>(pts, centers, gkeys, patches);
}

// Round 7
// 224.015 us; speedup vs baseline: 2.2774x; 1.3100x over previous
//
#include <hip/hip_runtime.h>
#include <float.h>

#define BATCH 16
#define NPTS  65536
#define NP    64      // NUM_PATCHES
#define PS    32      // PATCH_SIZE
#define SLICES 8
#define SLICE_PTS (NPTS / SLICES)   // 8192
#define CAP   192                   // per (center,slice) candidate cap (exp ~40)

// Selection math (FPS argmax, KNN top-32) is float64 on f32 inputs (products
// of f32 exact in f64 -> bit-identical to numpy f64 regardless of FMA), with
// numpy expression order: ((a+b)+c), d2 = (c2+p2) - 2*dot, contract(off).
// Keys: trunc-48-bit f64 ordering bits | 16-bit index -> (dist, idx) lex order.

__device__ __forceinline__ unsigned long long enc64(double d) {
    unsigned long long u = (unsigned long long)__double_as_longlong(d);
    return u ^ ((u >> 63) ? 0xFFFFFFFFFFFFFFFFull : 0x8000000000000000ull);
}
__device__ __forceinline__ unsigned enc32(float f) {
    unsigned u = __float_as_uint(f);
    return u ^ ((u >> 31) ? 0xFFFFFFFFu : 0x80000000u);
}
__device__ __forceinline__ float dec32(unsigned e) {
    unsigned u = (e & 0x80000000u) ? (e ^ 0x80000000u) : ~e;
    return __uint_as_float(u);
}

#define SENT 0xFFFFFFFFFFFFFFFFull

// ---------------------------------------------------------------------------
// FPS (v1, known-good 117us — PERMANENT: sync-restructure 0-for-3, R2/R5
// post-mortems; 117us ~ 1.25x the 63-round cross-CU sync floor). 16 WGs per
// batch (blockIdx = wg*16+b -> all WGs of batch b on XCD b%8), 256 threads,
// 16 pts/thread in VGPRs. Relaxed agent atomics only. 2 barriers per round.
// ---------------------------------------------------------------------------
__global__ __launch_bounds__(256, 2)
void fps_kernel(const float* __restrict__ pts,
                float* __restrict__ centers,               // [16][64][3]
                unsigned long long* __restrict__ slots)    // [16][63][16], zeroed
{
#pragma clang fp contract(off)
    const int b  = blockIdx.x & 15;
    const int wg = blockIdx.x >> 4;
    const int t  = threadIdx.x;
    const float* __restrict__ P = pts + (size_t)b * NPTS * 3;

    float x[16], y[16], z[16];
    double md[16];
    const int gi0 = wg * 4096 + t;
#pragma unroll
    for (int k = 0; k < 16; ++k) {
        int i = gi0 + (k << 8);
        x[k] = P[3*i+0]; y[k] = P[3*i+1]; z[k] = P[3*i+2];
        md[k] = DBL_MAX;
    }

    double cx = (double)P[0], cy = (double)P[1], cz = (double)P[2]; // start idx 0
    if (wg == 0 && t == 0) {
        float* c0 = centers + b * (NP*3);
        c0[0] = P[0]; c0[1] = P[1]; c0[2] = P[2];
    }

    __shared__ unsigned long long wbest[4];
    __shared__ unsigned long long skey[16];

    unsigned long long* slot_it = slots + (size_t)b * 63 * 16;

    for (int it = 0; it < NP - 1; ++it) {
        double bd = -1.0; int bi = 0;
#pragma unroll
        for (int k = 0; k < 16; ++k) {
            double dx = (double)x[k] - cx;
            double dy = (double)y[k] - cy;
            double dz = (double)z[k] - cz;
            double d  = (dx*dx + dy*dy) + dz*dz;   // numpy add order (products exact)
            double m  = fmin(md[k], d);
            md[k] = m;
            if (m > bd) { bd = m; bi = gi0 + (k << 8); }  // strict >: first index wins
        }
        unsigned long long db  = (unsigned long long)__double_as_longlong(bd); // bd>=0
        unsigned long long key = 0x8000000000000000ull
                               | (db & 0xFFFFFFFFFFFF0000ull)
                               | (unsigned long long)((~bi) & 0xFFFF);
#pragma unroll
        for (int off = 32; off > 0; off >>= 1) {
            unsigned long long o = __shfl_xor(key, off, 64);
            if (o > key) key = o;
        }
        if ((t & 63) == 0) wbest[t >> 6] = key;
        __syncthreads();                                   // bar1
        if (t == 0) {
            unsigned long long k0 = wbest[0];
            if (wbest[1] > k0) k0 = wbest[1];
            if (wbest[2] > k0) k0 = wbest[2];
            if (wbest[3] > k0) k0 = wbest[3];
            __hip_atomic_store(slot_it + wg, k0, __ATOMIC_RELAXED, __HIP_MEMORY_SCOPE_AGENT);
        }
        if (t < 16) {
            unsigned long long v;
            v = __hip_atomic_load(slot_it + t, __ATOMIC_RELAXED, __HIP_MEMORY_SCOPE_AGENT);
            while (v == 0) {
                __builtin_amdgcn_s_sleep(1);
                v = __hip_atomic_load(slot_it + t, __ATOMIC_RELAXED, __HIP_MEMORY_SCOPE_AGENT);
            }
            skey[t] = v;
        }
        __syncthreads();                                   // bar2
        unsigned long long bk = skey[0];
#pragma unroll
        for (int j = 1; j < 16; ++j) if (skey[j] > bk) bk = skey[j];
        int sel = (int)((~bk) & 0xFFFFull);
        cx = (double)P[3*sel+0]; cy = (double)P[3*sel+1]; cz = (double)P[3*sel+2];
        if (wg == 0 && t == 0) {
            float* c = centers + b*(NP*3) + (it+1)*3;
            c[0] = P[3*sel+0]; c[1] = P[3*sel+1]; c[2] = P[3*sel+2];
        }
        slot_it += 16;
        // no trailing barrier: next round's bar1 orders skey/wbest reuse
    }
}

// ---------------------------------------------------------------------------
// KNN pass v5 (R6 counters: VALUBusy 72.8%, HBM 0.9% -> VALU-ISSUE-BOUND;
// REPS marginal: streaming ~33us, fixed ~52us of the ~85us single-rep wall).
// Two instruction-diet cuts, both exact-output-preserving:
//  (a) distance via fma chain: d2 = fma(-2cx,px,fma(-2cy,py,fma(-2cz,pz,c2)))
//      + p2 — 4 ops vs 5 per (pt,g), applied IDENTICALLY in pass1+pass2 so
//      the theta-capture invariant (pass2 d2 == pass1 d2) holds; rounding
//      shift ~1e-5 << 4e-3 margin; final selection is exact f64 in phase 3.
//  (b) phase-3 top-32 via COUNTING-RANK instead of 32 serial rounds of
//      64-lane 64-bit shuffle-min (each ~6 chained ds_bpermute pairs): keys
//      to LDS (union over dead pool storage, zero LDS growth), then
//      rank[j] = #{keys < rg[j]} by broadcast-read loop (~6 VALU/iter, no
//      serial chains). Keys unique (idx embedded) -> ranks are exact sorted
//      positions -> gkeys output bit-identical (theta guarantees n>=32, so
//      ranks 0..31 always filled, matching the old SENT-free first 32).
// Structure otherwise R3 known-good: 2048 WGs x 256 thr, CG=4, b=&15,
// w=(>>4)&15, s=>>8; pass1 top-2 (med3) -> pool -> theta = 32nd + 4e-3;
// pass2 rescan with per-lane atomicAdd compaction (order-free).
// ---------------------------------------------------------------------------
__global__ __launch_bounds__(256, 4)
void knn_pass(const float* __restrict__ pts,
              const float* __restrict__ centers,
              unsigned long long* __restrict__ gkeys)   // [1024][8][32]
{
    const int t    = threadIdx.x;
    const int lane = t & 63;
    const int wid  = t >> 6;             // 0..3
    const int b    = blockIdx.x & 15;
    const int w    = (blockIdx.x >> 4) & 15;
    const int s    = blockIdx.x >> 8;    // 0..7
    const float* __restrict__ P = pts + (size_t)b * NPTS * 3;
    const int sbase = s * SLICE_PTS;
    const float4* __restrict__ P4 = (const float4*)(P + 3 * sbase);

    float m2x[4], m2y[4], m2z[4], c2f[4];
#pragma unroll
    for (int g = 0; g < 4; ++g) {
        int c = b * NP + w * 4 + g;
        float cx = centers[3*c+0], cy = centers[3*c+1], cz = centers[3*c+2];
        c2f[g] = cx*cx + cy*cy + cz*cz;
        m2x[g] = -2.0f*cx; m2y[g] = -2.0f*cy; m2z[g] = -2.0f*cz;
    }

    union PoolKeys {
        unsigned pool[4][512];             // pass1/theta (8 KB)
        unsigned long long keys[4][CAP];   // phase 3 (6 KB) — pool is dead by then
    };
    __shared__ PoolKeys pk;
    __shared__ float    theta4[4];
    __shared__ int      cnt4[4];
    __shared__ unsigned idxbuf[4][CAP];

    // ---- pass 1: per-thread top-2 (f32), 4 pts/iter, prefetch k+1 ----
    float s0[4], s1[4];
#pragma unroll
    for (int g = 0; g < 4; ++g) { s0[g] = FLT_MAX; s1[g] = FLT_MAX; }
    {
        float4 A = P4[3*t], B = P4[3*t+1], C = P4[3*t+2];
        for (int k = 0; k < SLICE_PTS/1024; ++k) {       // 8 iterations
            int vb = ((k+1) & 7)*768 + 3*t;              // wrap: last prefetch discarded
            float4 An = P4[vb], Bn = P4[vb+1], Cn = P4[vb+2];
            float qx[4] = {A.x, A.w, B.z, C.y};
            float qy[4] = {A.y, B.x, B.w, C.z};
            float qz[4] = {A.z, B.y, C.x, C.w};
#pragma unroll
            for (int j = 0; j < 4; ++j) {
                float px = qx[j], py = qy[j], pz = qz[j];
                float p2 = px*px + py*py + pz*pz;
#pragma unroll
                for (int g = 0; g < 4; ++g) {
                    float d2 = fmaf(m2x[g], px, fmaf(m2y[g], py, fmaf(m2z[g], pz, c2f[g]))) + p2;
                    s1[g] = __builtin_amdgcn_fmed3f(s0[g], s1[g], d2);   // exact 2nd-min
                    s0[g] = fminf(s0[g], d2);
                }
            }
            A = An; B = Bn; C = Cn;
        }
    }
#pragma unroll
    for (int g = 0; g < 4; ++g) {
        pk.pool[g][t]       = enc32(s0[g]);
        pk.pool[g][256 + t] = enc32(s1[g]);
    }
    if (t < 4) cnt4[t] = 0;
    __syncthreads();

    // ---- theta: wave wid finds 32nd smallest of pool[wid][0..511] ----
    {
        const int g = wid;
        unsigned e[8];
#pragma unroll
        for (int j = 0; j < 8; ++j) e[j] = pk.pool[g][lane * 8 + j];
        unsigned ans = 0;
        for (int bit = 31; bit >= 0; --bit) {
            unsigned test = ans | ((1u << bit) - 1u);
            int cnt = 0;
#pragma unroll
            for (int j = 0; j < 8; ++j)
                cnt += (int)__popcll(__ballot(e[j] <= test));
            if (cnt < 32) ans |= (1u << bit);
        }
        if (lane == 0) theta4[g] = dec32(ans) + 4.0e-3f;
    }
    __syncthreads();
    float th[4];
#pragma unroll
    for (int g = 0; g < 4; ++g) th[g] = theta4[g];

    // ---- pass 2: f32 rescan with prefetch, atomicAdd compaction ----
    {
        float4 A = P4[3*t], B = P4[3*t+1], C = P4[3*t+2];
        for (int k = 0; k < SLICE_PTS/1024; ++k) {
            int vb = ((k+1) & 7)*768 + 3*t;
            float4 An = P4[vb], Bn = P4[vb+1], Cn = P4[vb+2];
            float qx[4] = {A.x, A.w, B.z, C.y};
            float qy[4] = {A.y, B.x, B.w, C.z};
            float qz[4] = {A.z, B.y, C.x, C.w};
            int ib = sbase + (k << 10) + (t << 2);
#pragma unroll
            for (int j = 0; j < 4; ++j) {
                float px = qx[j], py = qy[j], pz = qz[j];
                float p2 = px*px + py*py + pz*pz;
#pragma unroll
                for (int g = 0; g < 4; ++g) {
                    float d2 = fmaf(m2x[g], px, fmaf(m2y[g], py, fmaf(m2z[g], pz, c2f[g]))) + p2;
                    if (d2 <= th[g]) {
                        int pos = atomicAdd(&cnt4[g], 1);
                        if (pos < CAP) idxbuf[g][pos] = (unsigned)(ib + j);
                    }
                }
            }
            A = An; B = Bn; C = Cn;
        }
    }
    __syncthreads();   // idxbuf/cnt4 complete; pool dead -> pk.keys reusable

    // ---- phase 3: wave wid -> center wid: f64 keys + counting-rank top-32 ----
    {
        const int g = wid;
        int n = cnt4[g]; if (n > CAP) n = CAP;
        double cxd, cyd, czd, c2d;
        {
#pragma clang fp contract(off)
            cxd = -0.5*(double)m2x[g]; cyd = -0.5*(double)m2y[g]; czd = -0.5*(double)m2z[g];
            c2d = (cxd*cxd + cyd*cyd) + czd*czd;
        }
        unsigned long long rg[3];
#pragma unroll
        for (int j = 0; j < 3; ++j) {
            int p_ = lane + 64*j;
            if (p_ < n) {
                unsigned i = idxbuf[g][p_];
                double d2x;
                {
#pragma clang fp contract(off)
                    double px_ = (double)P[3*i+0];
                    double py_ = (double)P[3*i+1];
                    double pz_ = (double)P[3*i+2];
                    double p2_ = (px_*px_ + py_*py_) + pz_*pz_;
                    double dt_ = (cxd*px_ + cyd*py_) + czd*pz_;
                    d2x = (c2d + p2_) - 2.0*dt_;
                }
                rg[j] = (enc64(d2x) & 0xFFFFFFFFFFFF0000ull)
                      | (unsigned long long)(i & 0xFFFF);
                pk.keys[g][p_] = rg[j];
            } else rg[j] = SENT;
        }
        // same-wave ds_write -> ds_read ordering (compiler inserts lgkmcnt)
        const int c = b * NP + w * 4 + g;
        int rank0 = 0, rank1 = 0, rank2 = 0;
        for (int p = 0; p < n; ++p) {
            unsigned long long kj = pk.keys[g][p];   // broadcast read
            rank0 += (kj < rg[0]);
            rank1 += (kj < rg[1]);
            rank2 += (kj < rg[2]);
        }
        unsigned long long* gout = gkeys + ((size_t)c * SLICES + s) * PS;
        if (lane       < n && rank0 < PS) gout[rank0] = rg[0];
        if (lane + 64  < n && rank1 < PS) gout[rank1] = rg[1];
        if (lane + 128 < n && rank2 < PS) gout[rank2] = rg[2];
        // theta guarantees n >= 32 -> ranks 0..31 all filled (keys unique).
    }
}

// ---------------------------------------------------------------------------
// Merge: 256 WGs x 256 thr; wave wid handles center b*64+grp*4+wid. Reads 8
// sorted 32-key lists (256 keys, 4/lane), 32 extraction rounds -> global
// top-32 in lax.top_k order; lanes 0..31 gather P and write patch rows.
// ---------------------------------------------------------------------------
__global__ __launch_bounds__(256, 4)
void knn_merge(const float* __restrict__ pts,
               const float* __restrict__ centers,
               const unsigned long long* __restrict__ gkeys,
               float* __restrict__ patches)
{
    const int lane = threadIdx.x & 63;
    const int wid  = threadIdx.x >> 6;
    const int b    = blockIdx.x & 15;
    const int grp  = blockIdx.x >> 4;
    const int c    = b * NP + grp * 4 + wid;
    const float* __restrict__ P = pts + (size_t)b * NPTS * 3;

    unsigned long long rg[4];
#pragma unroll
    for (int j = 0; j < 4; ++j)
        rg[j] = gkeys[(size_t)c * (SLICES*PS) + j*64 + lane];

    unsigned long long okey = SENT;
    for (int r = 0; r < PS; ++r) {
        unsigned long long mn = rg[0]; int mp = 0;
        if (rg[1] < mn) { mn = rg[1]; mp = 1; }
        if (rg[2] < mn) { mn = rg[2]; mp = 2; }
        if (rg[3] < mn) { mn = rg[3]; mp = 3; }
        unsigned long long wm = mn;
#pragma unroll
        for (int off = 32; off > 0; off >>= 1) {
            unsigned long long o = __shfl_xor(wm, off, 64);
            if (o < wm) wm = o;
        }
        if (wm == mn) {
            if (mp == 0) rg[0] = SENT;
            else if (mp == 1) rg[1] = SENT;
            else if (mp == 2) rg[2] = SENT;
            else rg[3] = SENT;
        }
        if (lane == r) okey = wm;
    }

    const float cx = centers[3*c+0], cy = centers[3*c+1], cz = centers[3*c+2];
    if (lane < PS) {
        int i = (int)(okey & 0xFFFFull);
        float* o = patches + (((size_t)c * PS) + lane) * 3;
        o[0] = P[3*i+0] - cx;
        o[1] = P[3*i+1] - cy;
        o[2] = P[3*i+2] - cz;
    }
}

extern "C" void kernel_launch(void* const* d_in, const int* in_sizes, int n_in,
                              void* d_out, int out_size, void* d_ws, size_t ws_size,
                              hipStream_t stream)
{
    const float* pts = (const float*)d_in[0];
    float* out      = (float*)d_out;
    float* patches  = out;                          // [16][64][32][3] = 98304
    float* centers  = out + (size_t)BATCH*NP*PS*3;  // [16][64][3]     = 3072

    unsigned long long* slots = (unsigned long long*)d_ws;                   // 129 KB
    unsigned long long* gkeys = (unsigned long long*)((char*)d_ws + 131072); // 2 MB

    (void)hipMemsetAsync(d_ws, 0, (size_t)BATCH * 63 * 16 * sizeof(unsigned long long), stream);
    fps_kernel<<<dim3(256), dim3(256), 0, stream>>>(pts, centers, slots);
    knn_pass<<<dim3(2048), dim3(256), 0, stream>>>(pts, centers, gkeys);
    knn_merge<<<dim3(256), dim3(256), 0, stream>>>(pts, centers, gkeys, patches);
}

// Round 8
// 212.111 us; speedup vs baseline: 2.4052x; 1.0561x over previous
//
#include <hip/hip_runtime.h>
#include <float.h>

#define BATCH 16
#define NPTS  65536
#define NP    64      // NUM_PATCHES
#define PS    32      // PATCH_SIZE
#define SLICES 4      // R8: was 8 — halves WG count (fixed-cost halving); 1024
                      // WGs = exactly 4/CU (single tranche at LB(256,4))
#define SLICE_PTS (NPTS / SLICES)   // 16384
#define CAP   256                   // per (center,slice) cap (exp ~80, 3.2x headroom)

// Selection math (FPS argmax, KNN top-32) is float64 on f32 inputs (products
// of f32 exact in f64 -> bit-identical to numpy f64 regardless of FMA), with
// numpy expression order: ((a+b)+c), d2 = (c2+p2) - 2*dot, contract(off).
// Keys: trunc-48-bit f64 ordering bits | 16-bit index -> (dist, idx) lex order.

__device__ __forceinline__ unsigned long long enc64(double d) {
    unsigned long long u = (unsigned long long)__double_as_longlong(d);
    return u ^ ((u >> 63) ? 0xFFFFFFFFFFFFFFFFull : 0x8000000000000000ull);
}
__device__ __forceinline__ unsigned enc32(float f) {
    unsigned u = __float_as_uint(f);
    return u ^ ((u >> 31) ? 0xFFFFFFFFu : 0x80000000u);
}
__device__ __forceinline__ float dec32(unsigned e) {
    unsigned u = (e & 0x80000000u) ? (e ^ 0x80000000u) : ~e;
    return __uint_as_float(u);
}

#define SENT 0xFFFFFFFFFFFFFFFFull

// ---------------------------------------------------------------------------
// FPS (v1, known-good 117us — PERMANENT: sync-restructure 0-for-3, R2/R5
// post-mortems; 117us ~ 1.25x the 63-round cross-CU sync floor). 16 WGs per
// batch (blockIdx = wg*16+b -> all WGs of batch b on XCD b%8), 256 threads,
// 16 pts/thread in VGPRs. Relaxed agent atomics only. 2 barriers per round.
// ---------------------------------------------------------------------------
__global__ __launch_bounds__(256, 2)
void fps_kernel(const float* __restrict__ pts,
                float* __restrict__ centers,               // [16][64][3]
                unsigned long long* __restrict__ slots)    // [16][63][16], zeroed
{
#pragma clang fp contract(off)
    const int b  = blockIdx.x & 15;
    const int wg = blockIdx.x >> 4;
    const int t  = threadIdx.x;
    const float* __restrict__ P = pts + (size_t)b * NPTS * 3;

    float x[16], y[16], z[16];
    double md[16];
    const int gi0 = wg * 4096 + t;
#pragma unroll
    for (int k = 0; k < 16; ++k) {
        int i = gi0 + (k << 8);
        x[k] = P[3*i+0]; y[k] = P[3*i+1]; z[k] = P[3*i+2];
        md[k] = DBL_MAX;
    }

    double cx = (double)P[0], cy = (double)P[1], cz = (double)P[2]; // start idx 0
    if (wg == 0 && t == 0) {
        float* c0 = centers + b * (NP*3);
        c0[0] = P[0]; c0[1] = P[1]; c0[2] = P[2];
    }

    __shared__ unsigned long long wbest[4];
    __shared__ unsigned long long skey[16];

    unsigned long long* slot_it = slots + (size_t)b * 63 * 16;

    for (int it = 0; it < NP - 1; ++it) {
        double bd = -1.0; int bi = 0;
#pragma unroll
        for (int k = 0; k < 16; ++k) {
            double dx = (double)x[k] - cx;
            double dy = (double)y[k] - cy;
            double dz = (double)z[k] - cz;
            double d  = (dx*dx + dy*dy) + dz*dz;   // numpy add order (products exact)
            double m  = fmin(md[k], d);
            md[k] = m;
            if (m > bd) { bd = m; bi = gi0 + (k << 8); }  // strict >: first index wins
        }
        unsigned long long db  = (unsigned long long)__double_as_longlong(bd); // bd>=0
        unsigned long long key = 0x8000000000000000ull
                               | (db & 0xFFFFFFFFFFFF0000ull)
                               | (unsigned long long)((~bi) & 0xFFFF);
#pragma unroll
        for (int off = 32; off > 0; off >>= 1) {
            unsigned long long o = __shfl_xor(key, off, 64);
            if (o > key) key = o;
        }
        if ((t & 63) == 0) wbest[t >> 6] = key;
        __syncthreads();                                   // bar1
        if (t == 0) {
            unsigned long long k0 = wbest[0];
            if (wbest[1] > k0) k0 = wbest[1];
            if (wbest[2] > k0) k0 = wbest[2];
            if (wbest[3] > k0) k0 = wbest[3];
            __hip_atomic_store(slot_it + wg, k0, __ATOMIC_RELAXED, __HIP_MEMORY_SCOPE_AGENT);
        }
        if (t < 16) {
            unsigned long long v;
            v = __hip_atomic_load(slot_it + t, __ATOMIC_RELAXED, __HIP_MEMORY_SCOPE_AGENT);
            while (v == 0) {
                __builtin_amdgcn_s_sleep(1);
                v = __hip_atomic_load(slot_it + t, __ATOMIC_RELAXED, __HIP_MEMORY_SCOPE_AGENT);
            }
            skey[t] = v;
        }
        __syncthreads();                                   // bar2
        unsigned long long bk = skey[0];
#pragma unroll
        for (int j = 1; j < 16; ++j) if (skey[j] > bk) bk = skey[j];
        int sel = (int)((~bk) & 0xFFFFull);
        cx = (double)P[3*sel+0]; cy = (double)P[3*sel+1]; cz = (double)P[3*sel+2];
        if (wg == 0 && t == 0) {
            float* c = centers + b*(NP*3) + (it+1)*3;
            c[0] = P[3*sel+0]; c[1] = P[3*sel+1]; c[2] = P[3*sel+2];
        }
        slot_it += 16;
        // no trailing barrier: next round's bar1 orders skey/wbest reuse
    }
}

// ---------------------------------------------------------------------------
// KNN pass v6 (R7 confirmed VALU-issue-bound; diet won −36us). R8: SLICES
// 8->4 — 1024 WGs (= 4/CU, one tranche), halving all per-WG fixed costs
// (theta radix-select, phase-3 setup) at unchanged streaming work. CAP 256.
// blockIdx: b=&15 (XCD-local batch), w=(>>4)&15 (center group of 4), s=>>8
// (slice of 16384). Pass 1: per-thread top-2 via fma-chain d2 + med3 ->
// pool[4][512] -> theta = 32nd smallest + 4e-3 (pool read j*64+lane:
// conflict-free, count is order-agnostic). Pass 2: identical d2, per-lane
// atomicAdd compaction (order-free). Phase 3: exact f64 keys for <=CAP
// candidates (4/lane), counting-rank top-32 (keys unique -> ranks exact;
// theta guarantees n>=32 -> ranks 0..31 filled) -> gkeys[c][s][32].
// ---------------------------------------------------------------------------
__global__ __launch_bounds__(256, 4)
void knn_pass(const float* __restrict__ pts,
              const float* __restrict__ centers,
              unsigned long long* __restrict__ gkeys)   // [1024][4][32]
{
    const int t    = threadIdx.x;
    const int lane = t & 63;
    const int wid  = t >> 6;             // 0..3
    const int b    = blockIdx.x & 15;
    const int w    = (blockIdx.x >> 4) & 15;
    const int s    = blockIdx.x >> 8;    // 0..3
    const float* __restrict__ P = pts + (size_t)b * NPTS * 3;
    const int sbase = s * SLICE_PTS;
    const float4* __restrict__ P4 = (const float4*)(P + 3 * sbase);

    float m2x[4], m2y[4], m2z[4], c2f[4];
#pragma unroll
    for (int g = 0; g < 4; ++g) {
        int c = b * NP + w * 4 + g;
        float cx = centers[3*c+0], cy = centers[3*c+1], cz = centers[3*c+2];
        c2f[g] = cx*cx + cy*cy + cz*cz;
        m2x[g] = -2.0f*cx; m2y[g] = -2.0f*cy; m2z[g] = -2.0f*cz;
    }

    union PoolKeys {
        unsigned pool[4][512];             // pass1/theta (8 KB)
        unsigned long long keys[4][CAP];   // phase 3 (8 KB) — pool dead by then
    };
    __shared__ PoolKeys pk;
    __shared__ float    theta4[4];
    __shared__ int      cnt4[4];
    __shared__ unsigned idxbuf[4][CAP];    // 4 KB

    // ---- pass 1: per-thread top-2 (f32), 4 pts/iter, prefetch k+1 ----
    float s0[4], s1[4];
#pragma unroll
    for (int g = 0; g < 4; ++g) { s0[g] = FLT_MAX; s1[g] = FLT_MAX; }
    {
        float4 A = P4[3*t], B = P4[3*t+1], C = P4[3*t+2];
        for (int k = 0; k < SLICE_PTS/1024; ++k) {       // 16 iterations
            int vb = ((k+1) & 15)*768 + 3*t;             // wrap: last prefetch discarded
            float4 An = P4[vb], Bn = P4[vb+1], Cn = P4[vb+2];
            float qx[4] = {A.x, A.w, B.z, C.y};
            float qy[4] = {A.y, B.x, B.w, C.z};
            float qz[4] = {A.z, B.y, C.x, C.w};
#pragma unroll
            for (int j = 0; j < 4; ++j) {
                float px = qx[j], py = qy[j], pz = qz[j];
                float p2 = px*px + py*py + pz*pz;
#pragma unroll
                for (int g = 0; g < 4; ++g) {
                    float d2 = fmaf(m2x[g], px, fmaf(m2y[g], py, fmaf(m2z[g], pz, c2f[g]))) + p2;
                    s1[g] = __builtin_amdgcn_fmed3f(s0[g], s1[g], d2);   // exact 2nd-min
                    s0[g] = fminf(s0[g], d2);
                }
            }
            A = An; B = Bn; C = Cn;
        }
    }
#pragma unroll
    for (int g = 0; g < 4; ++g) {
        pk.pool[g][t]       = enc32(s0[g]);
        pk.pool[g][256 + t] = enc32(s1[g]);
    }
    if (t < 4) cnt4[t] = 0;
    __syncthreads();

    // ---- theta: wave wid finds 32nd smallest of pool[wid][0..511] ----
    {
        const int g = wid;
        unsigned e[8];
#pragma unroll
        for (int j = 0; j < 8; ++j) e[j] = pk.pool[g][j * 64 + lane];  // conflict-free
        unsigned ans = 0;
        for (int bit = 31; bit >= 0; --bit) {
            unsigned test = ans | ((1u << bit) - 1u);
            int cnt = 0;
#pragma unroll
            for (int j = 0; j < 8; ++j)
                cnt += (int)__popcll(__ballot(e[j] <= test));
            if (cnt < 32) ans |= (1u << bit);
        }
        if (lane == 0) theta4[g] = dec32(ans) + 4.0e-3f;
    }
    __syncthreads();
    float th[4];
#pragma unroll
    for (int g = 0; g < 4; ++g) th[g] = theta4[g];

    // ---- pass 2: f32 rescan (identical d2), atomicAdd compaction ----
    {
        float4 A = P4[3*t], B = P4[3*t+1], C = P4[3*t+2];
        for (int k = 0; k < SLICE_PTS/1024; ++k) {
            int vb = ((k+1) & 15)*768 + 3*t;
            float4 An = P4[vb], Bn = P4[vb+1], Cn = P4[vb+2];
            float qx[4] = {A.x, A.w, B.z, C.y};
            float qy[4] = {A.y, B.x, B.w, C.z};
            float qz[4] = {A.z, B.y, C.x, C.w};
            int ib = sbase + (k << 10) + (t << 2);
#pragma unroll
            for (int j = 0; j < 4; ++j) {
                float px = qx[j], py = qy[j], pz = qz[j];
                float p2 = px*px + py*py + pz*pz;
#pragma unroll
                for (int g = 0; g < 4; ++g) {
                    float d2 = fmaf(m2x[g], px, fmaf(m2y[g], py, fmaf(m2z[g], pz, c2f[g]))) + p2;
                    if (d2 <= th[g]) {
                        int pos = atomicAdd(&cnt4[g], 1);
                        if (pos < CAP) idxbuf[g][pos] = (unsigned)(ib + j);
                    }
                }
            }
            A = An; B = Bn; C = Cn;
        }
    }
    __syncthreads();   // idxbuf/cnt4 complete; pool dead -> pk.keys reusable

    // ---- phase 3: wave wid -> center wid: f64 keys + counting-rank top-32 ----
    {
        const int g = wid;
        int n = cnt4[g]; if (n > CAP) n = CAP;
        double cxd, cyd, czd, c2d;
        {
#pragma clang fp contract(off)
            cxd = -0.5*(double)m2x[g]; cyd = -0.5*(double)m2y[g]; czd = -0.5*(double)m2z[g];
            c2d = (cxd*cxd + cyd*cyd) + czd*czd;
        }
        unsigned long long rg[4];
#pragma unroll
        for (int j = 0; j < 4; ++j) {
            int p_ = lane + 64*j;
            if (p_ < n) {
                unsigned i = idxbuf[g][p_];
                double d2x;
                {
#pragma clang fp contract(off)
                    double px_ = (double)P[3*i+0];
                    double py_ = (double)P[3*i+1];
                    double pz_ = (double)P[3*i+2];
                    double p2_ = (px_*px_ + py_*py_) + pz_*pz_;
                    double dt_ = (cxd*px_ + cyd*py_) + czd*pz_;
                    d2x = (c2d + p2_) - 2.0*dt_;
                }
                rg[j] = (enc64(d2x) & 0xFFFFFFFFFFFF0000ull)
                      | (unsigned long long)(i & 0xFFFF);
                pk.keys[g][p_] = rg[j];
            } else rg[j] = SENT;
        }
        // same-wave ds_write -> ds_read ordering (compiler inserts lgkmcnt)
        const int c = b * NP + w * 4 + g;
        int rk[4] = {0, 0, 0, 0};
        for (int p = 0; p < n; ++p) {
            unsigned long long kj = pk.keys[g][p];   // broadcast read
            rk[0] += (kj < rg[0]);
            rk[1] += (kj < rg[1]);
            rk[2] += (kj < rg[2]);
            rk[3] += (kj < rg[3]);
        }
        unsigned long long* gout = gkeys + ((size_t)c * SLICES + s) * PS;
#pragma unroll
        for (int j = 0; j < 4; ++j)
            if (lane + 64*j < n && rk[j] < PS) gout[rk[j]] = rg[j];
        // theta guarantees n >= 32 -> ranks 0..31 all filled (keys unique).
    }
}

// ---------------------------------------------------------------------------
// Merge v2 (counting-rank, replaces 32 serial shuffle-min extraction rounds
// ~12.8k cyc/wave with a ~128-iter broadcast loop ~650 cyc): 256 WGs x 256
// thr; wave wid = center b*64+grp*4+wid. 128 keys (4 slices x 32, 2/lane) ->
// LDS; rank = #{keys < mine} over 128 (keys unique -> exact sorted position
// = lax.top_k order, bit-identical to extraction); rank<32 -> gather P, write
// patch row 'rank'.
// ---------------------------------------------------------------------------
__global__ __launch_bounds__(256, 4)
void knn_merge(const float* __restrict__ pts,
               const float* __restrict__ centers,
               const unsigned long long* __restrict__ gkeys,
               float* __restrict__ patches)
{
    const int lane = threadIdx.x & 63;
    const int wid  = threadIdx.x >> 6;
    const int b    = blockIdx.x & 15;
    const int grp  = blockIdx.x >> 4;
    const int c    = b * NP + grp * 4 + wid;
    const float* __restrict__ P = pts + (size_t)b * NPTS * 3;

    __shared__ unsigned long long mk[4][SLICES*PS];   // 4 KB

    unsigned long long rg0 = gkeys[(size_t)c * (SLICES*PS) + lane];
    unsigned long long rg1 = gkeys[(size_t)c * (SLICES*PS) + 64 + lane];
    mk[wid][lane]      = rg0;
    mk[wid][64 + lane] = rg1;
    // all 128 entries written by this same wave; wave-internal lgkmcnt orders

    int r0 = 0, r1 = 0;
#pragma unroll 4
    for (int p = 0; p < SLICES*PS; ++p) {
        unsigned long long kj = mk[wid][p];          // broadcast read
        r0 += (kj < rg0);
        r1 += (kj < rg1);
    }

    const float cx = centers[3*c+0], cy = centers[3*c+1], cz = centers[3*c+2];
    if (r0 < PS) {
        int i = (int)(rg0 & 0xFFFFull);
        float* o = patches + (((size_t)c * PS) + r0) * 3;
        o[0] = P[3*i+0] - cx;
        o[1] = P[3*i+1] - cy;
        o[2] = P[3*i+2] - cz;
    }
    if (r1 < PS) {
        int i = (int)(rg1 & 0xFFFFull);
        float* o = patches + (((size_t)c * PS) + r1) * 3;
        o[0] = P[3*i+0] - cx;
        o[1] = P[3*i+1] - cy;
        o[2] = P[3*i+2] - cz;
    }
}

extern "C" void kernel_launch(void* const* d_in, const int* in_sizes, int n_in,
                              void* d_out, int out_size, void* d_ws, size_t ws_size,
                              hipStream_t stream)
{
    const float* pts = (const float*)d_in[0];
    float* out      = (float*)d_out;
    float* patches  = out;                          // [16][64][32][3] = 98304
    float* centers  = out + (size_t)BATCH*NP*PS*3;  // [16][64][3]     = 3072

    unsigned long long* slots = (unsigned long long*)d_ws;                   // 129 KB
    unsigned long long* gkeys = (unsigned long long*)((char*)d_ws + 131072); // 1 MB

    (void)hipMemsetAsync(d_ws, 0, (size_t)BATCH * 63 * 16 * sizeof(unsigned long long), stream);
    fps_kernel<<<dim3(256), dim3(256), 0, stream>>>(pts, centers, slots);
    knn_pass<<<dim3(1024), dim3(256), 0, stream>>>(pts, centers, gkeys);
    knn_merge<<<dim3(256), dim3(256), 0, stream>>>(pts, centers, gkeys, patches);
}